// Round 19
// baseline (37.240 us; speedup 1.0000x reference)
//
#include <hip/hip_runtime.h>
#include <hip/hip_bf16.h>
#include <math.h>

typedef __attribute__((ext_vector_type(8))) short short8;
typedef __attribute__((ext_vector_type(4))) float f32x4;
typedef __attribute__((ext_vector_type(16))) float f32x16;
typedef unsigned int u32;
typedef unsigned long long u64;

// fast round-to-nearest-even f32 -> bf16 (finite values)
__device__ __forceinline__ ushort f2bf(float f) {
    u32 u = __float_as_uint(f);
    return (ushort)((u + 0x7fffu + ((u >> 16) & 1u)) >> 16);
}
__device__ __forceinline__ float bf2f(ushort h) {
    return __uint_as_float(((u32)h) << 16);
}
// pack two f32 -> one u32 of 2 bf16 (RNE), single HW instr on gfx950
__device__ __forceinline__ u32 cvtpk_bf16(float a, float b) {
    u32 r;
    asm("v_cvt_pk_bf16_f32 %0, %1, %2" : "=v"(r) : "v"(a), "v"(b));
    return r;
}

#define RS 144   // Fs row stride in ushorts (K=144 exactly)

// ---------------------------------------------------------------------------
// Weight pack: layer_weight (32,144,3,3) f32 -> bf16 A-fragments for
// mfma_f32_32x32x16_bf16 (weights = A operand, M=32=oc, K=144).
// Page = tap*9 + ks. A-frag: row(oc) = lane&31, k = ks*16 + (lane>>5)*8 + e.
// k-order: k<128 -> spline (icg*8+jj), 128..143 -> gelu(icg).
// ---------------------------------------------------------------------------
__global__ void wtrans(const float* __restrict__ lw, ushort* __restrict__ w2) {
    int t = blockIdx.x * 256 + threadIdx.x;
    if (t >= 5184) return;
    int l    = t & 63;
    int page = t >> 6;          // 0..80
    int ks  = page % 9;
    int tap = page / 9;
    int oc = l & 31;
    int kbase = ks * 16 + ((l >> 5) << 3);
    short8 v;
#pragma unroll
    for (int e = 0; e < 8; ++e) {
        int k = kbase + e;      // < 144 always
        v[e] = (short)f2bf(lw[(oc * 144 + k) * 9 + tap]);
    }
    ((short8*)w2)[t] = v;
}

// ---------------------------------------------------------------------------
// MFMA implicit-GEMM KAN conv, 32x32x16 bf16, K=144. Raw bf16 y out.
// BARRIER-FREE WAVE STRUCTURE: block = (b, g, 8x16 tile), halo 10x18 = 180 px,
// Fs = 181 rows x 144 ushorts = 52.1 KB (row 180 = dump) -> 3 blocks/CU.
// Each of 4 waves owns one 2-row (32-pixel) subtile and computes FULL K=144
// over all 9 taps -> no partial combine, ONE barrier total.
// Band = bx%8 -> all (b,g) instances of a band land on one XCD (halo L2-local).
// ---------------------------------------------------------------------------
__global__ __launch_bounds__(256, 3) void kanconv(const float* __restrict__ x,
                                                  const ushort* __restrict__ w2,
                                                  ushort* __restrict__ yraw) {
    __shared__ __align__(16) ushort Fs[181 * RS];   // row 180 = dump row
    const int tid  = threadIdx.x;
    const int bx   = blockIdx.x;          // 0..31
    const int b    = blockIdx.y;
    const int g    = blockIdx.z;
    const int h0 = (bx & 7) * 8;          // band -> XCD-local
    const int w0 = (bx >> 3) * 16;
    const float* xg = x + ((size_t)(b * 64 + g * 16)) * 4096;

    // ---- phase 1: prefetch the 12 x values (independent loads) ----
    float xv[12];
    unsigned imgbits = 0;
#pragma unroll
    for (int it = 0; it < 12; ++it) {
        int e = it * 256 + tid;           // 0..3071, need < 2880
        float v = 0.f;
        if (e < 2880) {
            int icg = e / 180;
            int p   = e - icg * 180;
            int py = p / 18, px = p - py * 18;
            int hy = h0 + py - 1, wx = w0 + px - 1;
            if (((unsigned)hy < 64u) && ((unsigned)wx < 64u)) {
                v = xg[icg * 4096 + hy * 64 + wx];
                imgbits |= (1u << it);
            }
        }
        xv[it] = v;
    }

    // ---- phase 2: feature math + LDS writes (all 16 icg) ----
#pragma unroll
    for (int it = 0; it < 12; ++it) {
        int e = it * 256 + tid;
        int in_r = (e < 2880);
        int icg  = in_r ? (e / 180) : 15;
        int p    = e - icg * 180;
        int rowp = in_r ? p : 180;        // dump row for overflow
        bool img = (imgbits >> it) & 1u;
        float v = xv[it];
        // uniform cubic B-spline closed form; knots -2.2 + 0.4*i
        float tpos = (v + 2.2f) * 2.5f;
        float cf = floorf(tpos);
        int ci = (int)cf;
        float u = tpos - cf;
        float u2 = u * u, u3 = u2 * u, om = 1.f - u;
        float q0 = om * om * om * (1.f / 6.f);
        float q1 = (4.f - 6.f * u2 + 3.f * u3) * (1.f / 6.f);
        float q2 = (1.f + 3.f * u + 3.f * u2 - 3.f * u3) * (1.f / 6.f);
        float q3 = u3 * (1.f / 6.f);
        u64 Q = (u64)cvtpk_bf16(q0, q1) | ((u64)cvtpk_bf16(q2, q3) << 32);
        u64 lo = 0, hi = 0;
        if (img && ci >= 0 && ci <= 10) {
            int s = ci * 16 - 48;
            if (s < 0)        { lo = Q >> (-s); }
            else if (s < 64)  { lo = Q << s; hi = s ? (Q >> (64 - s)) : 0ull; }
            else              { hi = Q << (s - 64); }
        }
        union { u64 q[2]; short8 s8; } un;
        un.q[0] = lo; un.q[1] = hi;
        ushort* row = &Fs[rowp * RS];
        *(short8*)(row + icg * 8) = un.s8;
        // gelu (tanh form); v==0 -> ge==0 (pad ok)
        float x3 = v * v * v;
        float t2 = fmaf(0.0713548163f, x3, 1.5957691216f * v);
        float e2 = __expf(t2);
        float th = 1.f - 2.f / (e2 + 1.f);
        float ge = 0.5f * v * (1.f + th);
        row[128 + icg] = f2bf(ge);
    }
    __syncthreads();                       // the ONLY barrier

    // ---- MFMA: wave wv owns rows 2wv..2wv+1 (32 px), full K, all taps ----
    const int wv = tid >> 6;
    const int l  = tid & 63;
    const int la = l & 31, klo = l >> 5;
    const int prow = 2 * wv + (la >> 4);   // within-tile output row
    const int pcol = la & 15;
    const short8* w8 = (const short8*)w2;

    f32x16 acc;
#pragma unroll
    for (int i = 0; i < 16; ++i) acc[i] = 0.f;

#pragma unroll
    for (int tap = 0; tap < 9; ++tap) {
        const int kh = tap / 3, kw = tap - kh * 3;
        const ushort* fb = &Fs[((prow + kh) * 18 + (pcol + kw)) * RS + klo * 8];
        const short8* ap = w8 + tap * 576 + l;
#pragma unroll
        for (int ks = 0; ks < 9; ++ks) {
            short8 a  = ap[ks * 64];                      // weights (A)
            short8 bf = *(const short8*)(fb + ks * 16);   // features (B)
            acc = __builtin_amdgcn_mfma_f32_32x32x16_bf16(a, bf, acc, 0, 0, 0);
        }
    }

    // D: col(pixel) = lane&31, row(oc) = (r&3) + 8*(r>>2) + 4*klo
    ushort* yb = yraw + (((size_t)b * 128 + g * 32) * 64 + h0 + prow) * 64
                      + w0 + pcol;
#pragma unroll
    for (int r = 0; r < 16; ++r) {
        int oc = (r & 3) + 8 * (r >> 2) + 4 * klo;
        yb[(size_t)oc * 4096] = f2bf(acc[r]);
    }
}

// ---------------------------------------------------------------------------
// Instance-norm + PReLU from bf16 raw y: one block of 512 per (b,c); each
// thread owns 8 CONTIGUOUS values; 1 b128 load + 2 float4 stores per thread.
// ---------------------------------------------------------------------------
__global__ __launch_bounds__(512) void instnorm(const ushort* __restrict__ yraw,
                                                float* __restrict__ y,
                                                const float* __restrict__ prelu) {
    const int blk = blockIdx.x;  // b*128 + c
    const int tid = threadIdx.x;
    const short8* rp = (const short8*)(yraw + (size_t)blk * 4096);
    short8 a = rp[tid];
    float v[8];
#pragma unroll
    for (int j = 0; j < 8; ++j) v[j] = bf2f((ushort)a[j]);
    float s = 0.f, s2 = 0.f;
#pragma unroll
    for (int j = 0; j < 8; ++j) { s += v[j]; s2 += v[j] * v[j]; }
#pragma unroll
    for (int off = 32; off > 0; off >>= 1) {
        s  += __shfl_down(s, off);
        s2 += __shfl_down(s2, off);
    }
    __shared__ float red[16];
    int wave = tid >> 6;
    if ((tid & 63) == 0) { red[wave] = s; red[8 + wave] = s2; }
    __syncthreads();
    float S  = red[0] + red[1] + red[2] + red[3]
             + red[4] + red[5] + red[6] + red[7];
    float S2 = red[8] + red[9] + red[10] + red[11]
             + red[12] + red[13] + red[14] + red[15];
    float mean = S * (1.0f / 4096.0f);
    float var  = S2 * (1.0f / 4096.0f) - mean * mean;
    float rstd = rsqrtf(var + 1e-5f);
    float slope = prelu[(blk >> 5) & 3];
    float4* op = (float4*)(y + (size_t)blk * 4096) + tid * 2;
#pragma unroll
    for (int k = 0; k < 2; ++k) {
        float4 o;
        float t;
        t = (v[k * 4 + 0] - mean) * rstd; o.x = t >= 0.f ? t : slope * t;
        t = (v[k * 4 + 1] - mean) * rstd; o.y = t >= 0.f ? t : slope * t;
        t = (v[k * 4 + 2] - mean) * rstd; o.z = t >= 0.f ? t : slope * t;
        t = (v[k * 4 + 3] - mean) * rstd; o.w = t >= 0.f ? t : slope * t;
        op[k] = o;
    }
}

extern "C" void kernel_launch(void* const* d_in, const int* in_sizes, int n_in,
                              void* d_out, int out_size, void* d_ws, size_t ws_size,
                              hipStream_t stream) {
    const float* x     = (const float*)d_in[0];
    const float* lw    = (const float*)d_in[1];
    const float* prelu = (const float*)d_in[2];
    float*  out  = (float*)d_out;
    ushort* w2   = (ushort*)d_ws;                       // 82,944 B
    ushort* yraw = (ushort*)((char*)d_ws + 92160);      // 8 MB bf16 raw y

    wtrans<<<21, 256, 0, stream>>>(lw, w2);
    dim3 grid(32, 8, 4);
    kanconv<<<grid, 256, 0, stream>>>(x, w2, yraw);
    instnorm<<<1024, 512, 0, stream>>>(yraw, out, prelu);
}

// Round 20
// 36.900 us; speedup vs baseline: 1.0092x; 1.0092x over previous
//
#include <hip/hip_runtime.h>
#include <hip/hip_bf16.h>
#include <math.h>

typedef __attribute__((ext_vector_type(8))) short short8;
typedef __attribute__((ext_vector_type(4))) float f32x4;
typedef __attribute__((ext_vector_type(16))) float f32x16;
typedef unsigned int u32;
typedef unsigned long long u64;

// fast round-to-nearest-even f32 -> bf16 (finite values)
__device__ __forceinline__ ushort f2bf(float f) {
    u32 u = __float_as_uint(f);
    return (ushort)((u + 0x7fffu + ((u >> 16) & 1u)) >> 16);
}
__device__ __forceinline__ float bf2f(ushort h) {
    return __uint_as_float(((u32)h) << 16);
}
// pack two f32 -> one u32 of 2 bf16 (RNE), single HW instr on gfx950
__device__ __forceinline__ u32 cvtpk_bf16(float a, float b) {
    u32 r;
    asm("v_cvt_pk_bf16_f32 %0, %1, %2" : "=v"(r) : "v"(a), "v"(b));
    return r;
}

#define RS 144   // Fs row stride in ushorts (K=144 exactly, no pad)

// ---------------------------------------------------------------------------
// Weight pack: layer_weight (32,144,3,3) f32 -> bf16 A-fragments for
// mfma_f32_32x32x16_bf16 (weights = A operand, M=32=oc, K=144).
// Page = tap*9 + ks. A-frag: row(oc) = lane&31, k = ks*16 + (lane>>5)*8 + e.
// k-order: k<128 -> spline (icg*8+jj), 128..143 -> gelu(icg).
// ---------------------------------------------------------------------------
__global__ void wtrans(const float* __restrict__ lw, ushort* __restrict__ w2) {
    int t = blockIdx.x * 256 + threadIdx.x;
    if (t >= 5184) return;
    int l    = t & 63;
    int page = t >> 6;          // 0..80
    int ks  = page % 9;
    int tap = page / 9;
    int oc = l & 31;
    int kbase = ks * 16 + ((l >> 5) << 3);
    short8 v;
#pragma unroll
    for (int e = 0; e < 8; ++e) {
        int k = kbase + e;      // < 144 always
        v[e] = (short)f2bf(lw[(oc * 144 + k) * 9 + tap]);
    }
    ((short8*)w2)[t] = v;
}

// ---------------------------------------------------------------------------
// MFMA implicit-GEMM KAN conv, 32x32x16 bf16, K=144. Raw bf16 y out.
// Block = (b, g, 4x16 tile), halo 6x18 = 108 px, row stride 144 ushort
// (Fs = 31.4 KB -> 5 blocks/CU). XCD-band remap: tile = (x%8)*8 + x/8.
// Staging split in two icg-halves; branch-free via dump row 108.
// Tap ownership BALANCED: waves own taps {0,1},{2,3},{4,5},{6,7} and tap 8's
// 9 k-steps are split 3/2/2/2 across waves (21/20/20/20 ks-units).
// 6-slot stride-20 combine.
// ---------------------------------------------------------------------------
__global__ __launch_bounds__(256, 5) void kanconv(const float* __restrict__ x,
                                                  const ushort* __restrict__ w2,
                                                  ushort* __restrict__ yraw) {
    __shared__ __align__(16) ushort Fs[109 * RS];   // row 108 = dump row
    const int tid  = threadIdx.x;
    const int bx   = blockIdx.x;          // 0..63
    const int tile = ((bx & 7) << 3) | (bx >> 3);    // band = bx%8 -> XCD-local
    const int b    = blockIdx.y;
    const int g    = blockIdx.z;
    const int h0 = (tile >> 2) * 4;
    const int w0 = (tile & 3) * 16;
    const float* xg = x + ((size_t)(b * 64 + g * 16)) * 4096;

    // ---- prefetch all 8 x loads (two icg-halves share coords/mask) ----
    float xv1[4], xv2[4];
    unsigned imgbits = 0;
#pragma unroll
    for (int it = 0; it < 4; ++it) {
        int e = it * 256 + tid;
        int icg = e / 108;
        int p   = e - icg * 108;
        int py = p / 18, px = p - py * 18;
        int hy = h0 + py - 1, wx = w0 + px - 1;
        bool valid = (e < 864) && ((unsigned)hy < 64u) && ((unsigned)wx < 64u);
        int off = valid ? (icg * 4096 + hy * 64 + wx) : 0;
        float a = xg[off];
        float c = xg[off + 8 * 4096];
        if (!valid) { a = 0.f; c = 0.f; } else { imgbits |= (1u << it); }
        xv1[it] = a;
        xv2[it] = c;
    }

// stage one element: spline q's via funnel-shift + cvt_pk, tanh-form gelu
#define STAGE(V, IMGF, ROWP, SLOT)                                            \
    do {                                                                      \
        float v_ = (V);                                                       \
        float tpos_ = (v_ + 2.2f) * 2.5f;                                     \
        float cf_ = floorf(tpos_);                                            \
        int ci_ = (int)cf_;                                                   \
        float u_ = tpos_ - cf_;                                               \
        float u2_ = u_ * u_, u3_ = u2_ * u_, om_ = 1.f - u_;                  \
        float q0_ = om_ * om_ * om_ * (1.f / 6.f);                            \
        float q1_ = (4.f - 6.f * u2_ + 3.f * u3_) * (1.f / 6.f);              \
        float q2_ = (1.f + 3.f * u_ + 3.f * u2_ - 3.f * u3_) * (1.f / 6.f);   \
        float q3_ = u3_ * (1.f / 6.f);                                        \
        u64 Q_ = (u64)cvtpk_bf16(q0_, q1_)                                    \
               | ((u64)cvtpk_bf16(q2_, q3_) << 32);                           \
        u64 lo_ = 0, hi_ = 0;                                                 \
        if ((IMGF) && ci_ >= 0 && ci_ <= 10) {                                \
            int s_ = ci_ * 16 - 48;                                           \
            if (s_ < 0)       { lo_ = Q_ >> (-s_); }                          \
            else if (s_ < 64) { lo_ = Q_ << s_;                               \
                                hi_ = s_ ? (Q_ >> (64 - s_)) : 0ull; }        \
            else              { hi_ = Q_ << (s_ - 64); }                      \
        }                                                                     \
        union { u64 q[2]; short8 s8; } un_;                                   \
        un_.q[0] = lo_; un_.q[1] = hi_;                                       \
        ushort* row_ = &Fs[(ROWP) * RS];                                      \
        *(short8*)(row_ + (SLOT) * 8) = un_.s8;                               \
        float x3_ = v_ * v_ * v_;                                             \
        float t2_ = fmaf(0.0713548163f, x3_, 1.5957691216f * v_);             \
        float e2_ = __expf(t2_);                                              \
        float th_ = 1.f - 2.f / (e2_ + 1.f);                                  \
        float ge_ = 0.5f * v_ * (1.f + th_);                                  \
        row_[128 + (SLOT)] = f2bf(ge_);                                       \
    } while (0)

#define STAGE_IT(IT, XV, SB)                                                  \
    do {                                                                      \
        int e_ = (IT) * 256 + tid;                                            \
        int icg_ = e_ / 108;                                                  \
        int p_ = e_ - icg_ * 108;                                             \
        int rowp_ = (e_ < 864) ? p_ : 108;   /* dump row for overflow */      \
        bool im_ = (imgbits >> (IT)) & 1u;                                    \
        STAGE((XV)[IT], im_, rowp_, icg_ + (SB));                             \
    } while (0)

    // ---- half-1 staging (icg 0-7, k 0-63 + gelu 128-135) ----
    STAGE_IT(0, xv1, 0);
    STAGE_IT(1, xv1, 0);
    STAGE_IT(2, xv1, 0);
    STAGE_IT(3, xv1, 0);
    __syncthreads();

    const int wv = tid >> 6;
    const int l  = tid & 63;
    const int la = l & 31, klo = l >> 5;
    const int p0row = la >> 4, p0col = la & 15;   // tile0: rows 0-1; tile1: +2
    const short8* w8 = (const short8*)w2;

    f32x16 accA, accB;
#pragma unroll
    for (int i = 0; i < 16; ++i) { accA[i] = 0.f; accB[i] = 0.f; }

#define TAPKS(TAP, K0, K1)                                                     \
    do {                                                                       \
        const int kh_ = (TAP) / 3, kw_ = (TAP) - kh_ * 3;                      \
        const ushort* fb0_ =                                                   \
            &Fs[((p0row + kh_) * 18 + (p0col + kw_)) * RS + klo * 8];          \
        const ushort* fb1_ = fb0_ + 2 * 18 * RS;                               \
        const short8* ap_ = w8 + (TAP) * 576 + l;                              \
        _Pragma("unroll")                                                      \
        for (int ks_ = (K0); ks_ < (K1); ++ks_) {                              \
            short8 a_  = ap_[ks_ * 64];                                        \
            short8 b0_ = *(const short8*)(fb0_ + ks_ * 16);                    \
            short8 b1_ = *(const short8*)(fb1_ + ks_ * 16);                    \
            accA = __builtin_amdgcn_mfma_f32_32x32x16_bf16(a_, b0_, accA, 0, 0, 0); \
            accB = __builtin_amdgcn_mfma_f32_32x32x16_bf16(a_, b1_, accB, 0, 0, 0); \
        }                                                                      \
    } while (0)

    const int t0 = wv * 2, t1 = wv * 2 + 1;

    // ---- region A: half-2 staging interleaved with MFMA over half-1 K ----
    // tap-8 split (region A part, ks<4 reads only icg0-7):
    //   wave 0: tap8 ks0-2; wave 1: tap8 ks3
    STAGE_IT(0, xv2, 8);
    STAGE_IT(1, xv2, 8);
    TAPKS(t0, 0, 2);
    STAGE_IT(2, xv2, 8);
    TAPKS(t0, 2, 4);
    STAGE_IT(3, xv2, 8);
    TAPKS(t1, 0, 4);
    if (wv == 0)      TAPKS(8, 0, 3);
    else if (wv == 1) TAPKS(8, 3, 4);
    __syncthreads();

    // ---- region B: remaining K (icg 8-15 splines + all gelu) ----
    // tap-8 split (region B part): wave 1: ks4; wave 2: ks5-6; wave 3: ks7-8
    TAPKS(t0, 4, 9);
    TAPKS(t1, 4, 9);
    if (wv == 1)      TAPKS(8, 4, 5);
    else if (wv == 2) TAPKS(8, 5, 7);
    else if (wv == 3) TAPKS(8, 7, 9);
#undef TAPKS
#undef STAGE_IT
#undef STAGE

    // ---- combine: 6 slots [slot][lane] stride 20 f32 (30,720 B in Fs) ----
    __syncthreads();                      // all feature reads done
    float* comb = (float*)Fs;
    if (wv != 0) {                        // tile0 partials: waves 1,2,3 -> 0,1,2
        float* cp = comb + ((wv - 1) * 64 + l) * 20;
        *(f32x4*)(cp + 0)  = f32x4{accA[0], accA[1], accA[2], accA[3]};
        *(f32x4*)(cp + 4)  = f32x4{accA[4], accA[5], accA[6], accA[7]};
        *(f32x4*)(cp + 8)  = f32x4{accA[8], accA[9], accA[10], accA[11]};
        *(f32x4*)(cp + 12) = f32x4{accA[12], accA[13], accA[14], accA[15]};
    }
    if (wv != 1) {                        // tile1 partials: waves 0,2,3 -> 3,4,5
        int slot = (wv == 0) ? 3 : (2 + wv);
        float* cp = comb + (slot * 64 + l) * 20;
        *(f32x4*)(cp + 0)  = f32x4{accB[0], accB[1], accB[2], accB[3]};
        *(f32x4*)(cp + 4)  = f32x4{accB[4], accB[5], accB[6], accB[7]};
        *(f32x4*)(cp + 8)  = f32x4{accB[8], accB[9], accB[10], accB[11]};
        *(f32x4*)(cp + 12) = f32x4{accB[12], accB[13], accB[14], accB[15]};
    }
    __syncthreads();
    if (wv < 2) {
        f32x16 sum = (wv == 0) ? accA : accB;
        const int sbase = (wv == 0) ? 0 : 3;
#pragma unroll
        for (int s = 0; s < 3; ++s) {
            const float* cp = comb + ((sbase + s) * 64 + l) * 20;
            f32x4 c0 = *(const f32x4*)(cp + 0);
            f32x4 c1 = *(const f32x4*)(cp + 4);
            f32x4 c2 = *(const f32x4*)(cp + 8);
            f32x4 c3 = *(const f32x4*)(cp + 12);
#pragma unroll
            for (int r = 0; r < 4; ++r) {
                sum[r]      += c0[r];
                sum[r + 4]  += c1[r];
                sum[r + 8]  += c2[r];
                sum[r + 12] += c3[r];
            }
        }
        // D: col(pixel) = lane&31, row(oc) = (r&3) + 8*(r>>2) + 4*klo
        const int pix = wv * 32 + la;
        const int prow = pix >> 4, pcol = pix & 15;
        ushort* yb = yraw + (((size_t)b * 128 + g * 32) * 64 + h0 + prow) * 64
                          + w0 + pcol;
#pragma unroll
        for (int r = 0; r < 16; ++r) {
            int oc = (r & 3) + 8 * (r >> 2) + 4 * klo;
            yb[(size_t)oc * 4096] = f2bf(sum[r]);
        }
    }
}

// ---------------------------------------------------------------------------
// Instance-norm + PReLU from bf16 raw y: one block of 512 per (b,c); each
// thread owns 8 CONTIGUOUS values; 1 b128 load + 2 float4 stores per thread.
// ---------------------------------------------------------------------------
__global__ __launch_bounds__(512) void instnorm(const ushort* __restrict__ yraw,
                                                float* __restrict__ y,
                                                const float* __restrict__ prelu) {
    const int blk = blockIdx.x;  // b*128 + c
    const int tid = threadIdx.x;
    const short8* rp = (const short8*)(yraw + (size_t)blk * 4096);
    short8 a = rp[tid];
    float v[8];
#pragma unroll
    for (int j = 0; j < 8; ++j) v[j] = bf2f((ushort)a[j]);
    float s = 0.f, s2 = 0.f;
#pragma unroll
    for (int j = 0; j < 8; ++j) { s += v[j]; s2 += v[j] * v[j]; }
#pragma unroll
    for (int off = 32; off > 0; off >>= 1) {
        s  += __shfl_down(s, off);
        s2 += __shfl_down(s2, off);
    }
    __shared__ float red[16];
    int wave = tid >> 6;
    if ((tid & 63) == 0) { red[wave] = s; red[8 + wave] = s2; }
    __syncthreads();
    float S  = red[0] + red[1] + red[2] + red[3]
             + red[4] + red[5] + red[6] + red[7];
    float S2 = red[8] + red[9] + red[10] + red[11]
             + red[12] + red[13] + red[14] + red[15];
    float mean = S * (1.0f / 4096.0f);
    float var  = S2 * (1.0f / 4096.0f) - mean * mean;
    float rstd = rsqrtf(var + 1e-5f);
    float slope = prelu[(blk >> 5) & 3];
    float4* op = (float4*)(y + (size_t)blk * 4096) + tid * 2;
#pragma unroll
    for (int k = 0; k < 2; ++k) {
        float4 o;
        float t;
        t = (v[k * 4 + 0] - mean) * rstd; o.x = t >= 0.f ? t : slope * t;
        t = (v[k * 4 + 1] - mean) * rstd; o.y = t >= 0.f ? t : slope * t;
        t = (v[k * 4 + 2] - mean) * rstd; o.z = t >= 0.f ? t : slope * t;
        t = (v[k * 4 + 3] - mean) * rstd; o.w = t >= 0.f ? t : slope * t;
        op[k] = o;
    }
}

extern "C" void kernel_launch(void* const* d_in, const int* in_sizes, int n_in,
                              void* d_out, int out_size, void* d_ws, size_t ws_size,
                              hipStream_t stream) {
    const float* x     = (const float*)d_in[0];
    const float* lw    = (const float*)d_in[1];
    const float* prelu = (const float*)d_in[2];
    float*  out  = (float*)d_out;
    ushort* w2   = (ushort*)d_ws;                       // 82,944 B
    ushort* yraw = (ushort*)((char*)d_ws + 92160);      // 8 MB bf16 raw y

    wtrans<<<21, 256, 0, stream>>>(lw, w2);
    dim3 grid(64, 8, 4);
    kanconv<<<grid, 256, 0, stream>>>(x, w2, yraw);
    instnorm<<<1024, 512, 0, stream>>>(yraw, out, prelu);
}

// Round 21
// 34.708 us; speedup vs baseline: 1.0730x; 1.0632x over previous
//
#include <hip/hip_runtime.h>
#include <hip/hip_bf16.h>
#include <math.h>

typedef __attribute__((ext_vector_type(8))) short short8;
typedef __attribute__((ext_vector_type(4))) float f32x4;
typedef __attribute__((ext_vector_type(16))) float f32x16;
typedef unsigned int u32;
typedef unsigned long long u64;

// fast round-to-nearest-even f32 -> bf16 (finite values)
__device__ __forceinline__ ushort f2bf(float f) {
    u32 u = __float_as_uint(f);
    return (ushort)((u + 0x7fffu + ((u >> 16) & 1u)) >> 16);
}
__device__ __forceinline__ float bf2f(ushort h) {
    return __uint_as_float(((u32)h) << 16);
}
// pack two f32 -> one u32 of 2 bf16 (RNE), single HW instr on gfx950
__device__ __forceinline__ u32 cvtpk_bf16(float a, float b) {
    u32 r;
    asm("v_cvt_pk_bf16_f32 %0, %1, %2" : "=v"(r) : "v"(a), "v"(b));
    return r;
}

#define RS 144   // Fs row stride in ushorts (K=144 exactly, no pad)

// ---------------------------------------------------------------------------
// Weight pack: layer_weight (32,144,3,3) f32 -> bf16 A-fragments for
// mfma_f32_32x32x16_bf16 (weights = A operand, M=32=oc, K=144).
// Page = tap*9 + ks. A-frag: row(oc) = lane&31, k = ks*16 + (lane>>5)*8 + e.
// k-order: k<128 -> spline (icg*8+jj), 128..143 -> gelu(icg).
// ---------------------------------------------------------------------------
__global__ void wtrans(const float* __restrict__ lw, ushort* __restrict__ w2) {
    int t = blockIdx.x * 256 + threadIdx.x;
    if (t >= 5184) return;
    int l    = t & 63;
    int page = t >> 6;          // 0..80
    int ks  = page % 9;
    int tap = page / 9;
    int oc = l & 31;
    int kbase = ks * 16 + ((l >> 5) << 3);
    short8 v;
#pragma unroll
    for (int e = 0; e < 8; ++e) {
        int k = kbase + e;      // < 144 always
        v[e] = (short)f2bf(lw[(oc * 144 + k) * 9 + tap]);
    }
    ((short8*)w2)[t] = v;
}

// ---------------------------------------------------------------------------
// MFMA implicit-GEMM KAN conv, 32x32x16 bf16, K=144. Raw bf16 y out.
// Block = (bg, 4x16 tile), halo 6x18 = 108 px, row stride 144 ushort
// (Fs = 31.4 KB -> 5 blocks/CU).
// XCD affinity by (b,g) PAIR: linear id i -> XCD i%8; decode
// bg = (i&7)+8*((i>>3)&3), tile = i>>5. One XCD owns all 64 tiles of its
// 4 bg's -> x slice (1 MB), w2, and yraw slice all XCD-L2-local; halo
// reuse local in BOTH h and w directions.
// Staging split in two icg-halves; branch-free via dump row 108.
// Tap ownership BALANCED: waves own taps {0,1},{2,3},{4,5},{6,7}; tap 8's
// k-steps split 3/2/2/2 (21/20/20/20 ks-units). 6-slot stride-20 combine.
// ---------------------------------------------------------------------------
__global__ __launch_bounds__(256, 5) void kanconv(const float* __restrict__ x,
                                                  const ushort* __restrict__ w2,
                                                  ushort* __restrict__ yraw) {
    __shared__ __align__(16) ushort Fs[109 * RS];   // row 108 = dump row
    const int tid  = threadIdx.x;
    const int i    = blockIdx.x;          // 0..2047
    const int bg   = (i & 7) + 8 * ((i >> 3) & 3);  // bg%8 == i%8 -> XCD-local
    const int tile = i >> 5;              // 0..63
    const int h0 = (tile >> 2) * 4;
    const int w0 = (tile & 3) * 16;
    const float* xg = x + ((size_t)bg * 16) * 4096;

    // ---- prefetch all 8 x loads (two icg-halves share coords/mask) ----
    float xv1[4], xv2[4];
    unsigned imgbits = 0;
#pragma unroll
    for (int it = 0; it < 4; ++it) {
        int e = it * 256 + tid;
        int icg = e / 108;
        int p   = e - icg * 108;
        int py = p / 18, px = p - py * 18;
        int hy = h0 + py - 1, wx = w0 + px - 1;
        bool valid = (e < 864) && ((unsigned)hy < 64u) && ((unsigned)wx < 64u);
        int off = valid ? (icg * 4096 + hy * 64 + wx) : 0;
        float a = xg[off];
        float c = xg[off + 8 * 4096];
        if (!valid) { a = 0.f; c = 0.f; } else { imgbits |= (1u << it); }
        xv1[it] = a;
        xv2[it] = c;
    }

// stage one element: spline q's via funnel-shift + cvt_pk, tanh-form gelu
#define STAGE(V, IMGF, ROWP, SLOT)                                            \
    do {                                                                      \
        float v_ = (V);                                                       \
        float tpos_ = (v_ + 2.2f) * 2.5f;                                     \
        float cf_ = floorf(tpos_);                                            \
        int ci_ = (int)cf_;                                                   \
        float u_ = tpos_ - cf_;                                               \
        float u2_ = u_ * u_, u3_ = u2_ * u_, om_ = 1.f - u_;                  \
        float q0_ = om_ * om_ * om_ * (1.f / 6.f);                            \
        float q1_ = (4.f - 6.f * u2_ + 3.f * u3_) * (1.f / 6.f);              \
        float q2_ = (1.f + 3.f * u_ + 3.f * u2_ - 3.f * u3_) * (1.f / 6.f);   \
        float q3_ = u3_ * (1.f / 6.f);                                        \
        u64 Q_ = (u64)cvtpk_bf16(q0_, q1_)                                    \
               | ((u64)cvtpk_bf16(q2_, q3_) << 32);                           \
        u64 lo_ = 0, hi_ = 0;                                                 \
        if ((IMGF) && ci_ >= 0 && ci_ <= 10) {                                \
            int s_ = ci_ * 16 - 48;                                           \
            if (s_ < 0)       { lo_ = Q_ >> (-s_); }                          \
            else if (s_ < 64) { lo_ = Q_ << s_;                               \
                                hi_ = s_ ? (Q_ >> (64 - s_)) : 0ull; }        \
            else              { hi_ = Q_ << (s_ - 64); }                      \
        }                                                                     \
        union { u64 q[2]; short8 s8; } un_;                                   \
        un_.q[0] = lo_; un_.q[1] = hi_;                                       \
        ushort* row_ = &Fs[(ROWP) * RS];                                      \
        *(short8*)(row_ + (SLOT) * 8) = un_.s8;                               \
        float x3_ = v_ * v_ * v_;                                             \
        float t2_ = fmaf(0.0713548163f, x3_, 1.5957691216f * v_);             \
        float e2_ = __expf(t2_);                                              \
        float th_ = 1.f - 2.f / (e2_ + 1.f);                                  \
        float ge_ = 0.5f * v_ * (1.f + th_);                                  \
        row_[128 + (SLOT)] = f2bf(ge_);                                       \
    } while (0)

#define STAGE_IT(IT, XV, SB)                                                  \
    do {                                                                      \
        int e_ = (IT) * 256 + tid;                                            \
        int icg_ = e_ / 108;                                                  \
        int p_ = e_ - icg_ * 108;                                             \
        int rowp_ = (e_ < 864) ? p_ : 108;   /* dump row for overflow */      \
        bool im_ = (imgbits >> (IT)) & 1u;                                    \
        STAGE((XV)[IT], im_, rowp_, icg_ + (SB));                             \
    } while (0)

    // ---- half-1 staging (icg 0-7, k 0-63 + gelu 128-135) ----
    STAGE_IT(0, xv1, 0);
    STAGE_IT(1, xv1, 0);
    STAGE_IT(2, xv1, 0);
    STAGE_IT(3, xv1, 0);
    __syncthreads();

    const int wv = tid >> 6;
    const int l  = tid & 63;
    const int la = l & 31, klo = l >> 5;
    const int p0row = la >> 4, p0col = la & 15;   // tile0: rows 0-1; tile1: +2
    const short8* w8 = (const short8*)w2;

    f32x16 accA, accB;
#pragma unroll
    for (int i2 = 0; i2 < 16; ++i2) { accA[i2] = 0.f; accB[i2] = 0.f; }

#define TAPKS(TAP, K0, K1)                                                     \
    do {                                                                       \
        const int kh_ = (TAP) / 3, kw_ = (TAP) - kh_ * 3;                      \
        const ushort* fb0_ =                                                   \
            &Fs[((p0row + kh_) * 18 + (p0col + kw_)) * RS + klo * 8];          \
        const ushort* fb1_ = fb0_ + 2 * 18 * RS;                               \
        const short8* ap_ = w8 + (TAP) * 576 + l;                              \
        _Pragma("unroll")                                                      \
        for (int ks_ = (K0); ks_ < (K1); ++ks_) {                              \
            short8 a_  = ap_[ks_ * 64];                                        \
            short8 b0_ = *(const short8*)(fb0_ + ks_ * 16);                    \
            short8 b1_ = *(const short8*)(fb1_ + ks_ * 16);                    \
            accA = __builtin_amdgcn_mfma_f32_32x32x16_bf16(a_, b0_, accA, 0, 0, 0); \
            accB = __builtin_amdgcn_mfma_f32_32x32x16_bf16(a_, b1_, accB, 0, 0, 0); \
        }                                                                      \
    } while (0)

    const int t0 = wv * 2, t1 = wv * 2 + 1;

    // ---- region A: half-2 staging interleaved with MFMA over half-1 K ----
    // tap-8 split (region A part, ks<4 reads only icg0-7):
    //   wave 0: tap8 ks0-2; wave 1: tap8 ks3
    STAGE_IT(0, xv2, 8);
    STAGE_IT(1, xv2, 8);
    TAPKS(t0, 0, 2);
    STAGE_IT(2, xv2, 8);
    TAPKS(t0, 2, 4);
    STAGE_IT(3, xv2, 8);
    TAPKS(t1, 0, 4);
    if (wv == 0)      TAPKS(8, 0, 3);
    else if (wv == 1) TAPKS(8, 3, 4);
    __syncthreads();

    // ---- region B: remaining K (icg 8-15 splines + all gelu) ----
    // tap-8 split (region B part): wave 1: ks4; wave 2: ks5-6; wave 3: ks7-8
    TAPKS(t0, 4, 9);
    TAPKS(t1, 4, 9);
    if (wv == 1)      TAPKS(8, 4, 5);
    else if (wv == 2) TAPKS(8, 5, 7);
    else if (wv == 3) TAPKS(8, 7, 9);
#undef TAPKS
#undef STAGE_IT
#undef STAGE

    // ---- combine: 6 slots [slot][lane] stride 20 f32 (30,720 B in Fs) ----
    __syncthreads();                      // all feature reads done
    float* comb = (float*)Fs;
    if (wv != 0) {                        // tile0 partials: waves 1,2,3 -> 0,1,2
        float* cp = comb + ((wv - 1) * 64 + l) * 20;
        *(f32x4*)(cp + 0)  = f32x4{accA[0], accA[1], accA[2], accA[3]};
        *(f32x4*)(cp + 4)  = f32x4{accA[4], accA[5], accA[6], accA[7]};
        *(f32x4*)(cp + 8)  = f32x4{accA[8], accA[9], accA[10], accA[11]};
        *(f32x4*)(cp + 12) = f32x4{accA[12], accA[13], accA[14], accA[15]};
    }
    if (wv != 1) {                        // tile1 partials: waves 0,2,3 -> 3,4,5
        int slot = (wv == 0) ? 3 : (2 + wv);
        float* cp = comb + (slot * 64 + l) * 20;
        *(f32x4*)(cp + 0)  = f32x4{accB[0], accB[1], accB[2], accB[3]};
        *(f32x4*)(cp + 4)  = f32x4{accB[4], accB[5], accB[6], accB[7]};
        *(f32x4*)(cp + 8)  = f32x4{accB[8], accB[9], accB[10], accB[11]};
        *(f32x4*)(cp + 12) = f32x4{accB[12], accB[13], accB[14], accB[15]};
    }
    __syncthreads();
    if (wv < 2) {
        f32x16 sum = (wv == 0) ? accA : accB;
        const int sbase = (wv == 0) ? 0 : 3;
#pragma unroll
        for (int s = 0; s < 3; ++s) {
            const float* cp = comb + ((sbase + s) * 64 + l) * 20;
            f32x4 c0 = *(const f32x4*)(cp + 0);
            f32x4 c1 = *(const f32x4*)(cp + 4);
            f32x4 c2 = *(const f32x4*)(cp + 8);
            f32x4 c3 = *(const f32x4*)(cp + 12);
#pragma unroll
            for (int r = 0; r < 4; ++r) {
                sum[r]      += c0[r];
                sum[r + 4]  += c1[r];
                sum[r + 8]  += c2[r];
                sum[r + 12] += c3[r];
            }
        }
        // D: col(pixel) = lane&31, row(oc) = (r&3) + 8*(r>>2) + 4*klo
        const int pix = wv * 32 + la;
        const int prow = pix >> 4, pcol = pix & 15;
        ushort* yb = yraw + (((size_t)bg * 32) * 64 + h0 + prow) * 64
                          + w0 + pcol;
#pragma unroll
        for (int r = 0; r < 16; ++r) {
            int oc = (r & 3) + 8 * (r >> 2) + 4 * klo;
            yb[(size_t)oc * 4096] = f2bf(sum[r]);
        }
    }
}

// ---------------------------------------------------------------------------
// Instance-norm + PReLU from bf16 raw y: one block of 512 per channel; block
// i remapped so the channel's (b,g) lands on the XCD that produced it
// (i%8 == bg%8). Each thread owns 8 contiguous values.
// ---------------------------------------------------------------------------
__global__ __launch_bounds__(512) void instnorm(const ushort* __restrict__ yraw,
                                                float* __restrict__ y,
                                                const float* __restrict__ prelu) {
    const int i  = blockIdx.x;            // 0..1023
    const int bg = (i & 7) + 8 * ((i >> 3) & 3);   // matches kanconv's XCD map
    const int oc = i >> 5;                // 0..31
    const int blk = bg * 32 + oc;         // channel index b*128 + g*32 + oc
    const int tid = threadIdx.x;
    const short8* rp = (const short8*)(yraw + (size_t)blk * 4096);
    short8 a = rp[tid];
    float v[8];
#pragma unroll
    for (int j = 0; j < 8; ++j) v[j] = bf2f((ushort)a[j]);
    float s = 0.f, s2 = 0.f;
#pragma unroll
    for (int j = 0; j < 8; ++j) { s += v[j]; s2 += v[j] * v[j]; }
#pragma unroll
    for (int off = 32; off > 0; off >>= 1) {
        s  += __shfl_down(s, off);
        s2 += __shfl_down(s2, off);
    }
    __shared__ float red[16];
    int wave = tid >> 6;
    if ((tid & 63) == 0) { red[wave] = s; red[8 + wave] = s2; }
    __syncthreads();
    float S  = red[0] + red[1] + red[2] + red[3]
             + red[4] + red[5] + red[6] + red[7];
    float S2 = red[8] + red[9] + red[10] + red[11]
             + red[12] + red[13] + red[14] + red[15];
    float mean = S * (1.0f / 4096.0f);
    float var  = S2 * (1.0f / 4096.0f) - mean * mean;
    float rstd = rsqrtf(var + 1e-5f);
    float slope = prelu[(blk >> 5) & 3];
    float4* op = (float4*)(y + (size_t)blk * 4096) + tid * 2;
#pragma unroll
    for (int k = 0; k < 2; ++k) {
        float4 o;
        float t;
        t = (v[k * 4 + 0] - mean) * rstd; o.x = t >= 0.f ? t : slope * t;
        t = (v[k * 4 + 1] - mean) * rstd; o.y = t >= 0.f ? t : slope * t;
        t = (v[k * 4 + 2] - mean) * rstd; o.z = t >= 0.f ? t : slope * t;
        t = (v[k * 4 + 3] - mean) * rstd; o.w = t >= 0.f ? t : slope * t;
        op[k] = o;
    }
}

extern "C" void kernel_launch(void* const* d_in, const int* in_sizes, int n_in,
                              void* d_out, int out_size, void* d_ws, size_t ws_size,
                              hipStream_t stream) {
    const float* x     = (const float*)d_in[0];
    const float* lw    = (const float*)d_in[1];
    const float* prelu = (const float*)d_in[2];
    float*  out  = (float*)d_out;
    ushort* w2   = (ushort*)d_ws;                       // 82,944 B
    ushort* yraw = (ushort*)((char*)d_ws + 92160);      // 8 MB bf16 raw y

    wtrans<<<21, 256, 0, stream>>>(lw, w2);
    kanconv<<<2048, 256, 0, stream>>>(x, w2, yraw);
    instnorm<<<1024, 512, 0, stream>>>(yraw, out, prelu);
}